// Round 1
// baseline (16.257 us; speedup 1.0000x reference)
//
#include <hip/hip_runtime.h>
#include <math.h>

// Graphene tight-binding band energies, closed form.
// Per k-point: p = a_lat*kx/2, b = a_lat*ky/(2*sqrt(3)).
// All 9 lattice phases reduce to functions of cos(p), cos(b), sin(b):
//   f_re = -t * (2 cp cb + 2 cb^2 - 1)
//   f_im = -t * (2 sb (cp - cb))
//   e    = -2 t' * (2 cp^2 - 1 + 2 cp (4 cb^3 - 3 cb))
//   out  = (e -/+ sqrt(m^2 + f_re^2 + f_im^2)) * EV_TO_J   [ascending]

namespace {
constexpr double A_LAT_D = 2.46e-10;
constexpr float C_P  = (float)(A_LAT_D * 0.5);                      // a/2
constexpr float C_B  = (float)(A_LAT_D / (2.0 * 1.7320508075688772935)); // a/(2*sqrt3)
constexpr float T_EV  = 2.8f;
constexpr float TP_EV = 0.1f;
constexpr float M_EV  = 0.05f;
constexpr float EVJ   = 1.602176634e-19f;
}

__device__ __forceinline__ void graphene_point(float kx, float ky,
                                               float& lo, float& hi) {
    float p = kx * C_P;
    float b = ky * C_B;
    float cp = __cosf(p);
    float cb = __cosf(b);
    float sb = __sinf(b);
    float cb2 = cb * cb;
    float c3b = cb * (4.0f * cb2 - 3.0f);          // cos(3b)
    float fre = -T_EV * (2.0f * cp * cb + 2.0f * cb2 - 1.0f);
    float fim = -T_EV * (2.0f * sb * (cp - cb));
    float e   = -2.0f * TP_EV * (2.0f * cp * cp - 1.0f + 2.0f * cp * c3b);
    float r   = sqrtf(M_EV * M_EV + fre * fre + fim * fim);
    lo = (e - r) * EVJ;
    hi = (e + r) * EVJ;
}

__global__ __launch_bounds__(256)
void graphene_kernel(const float4* __restrict__ k4, float4* __restrict__ out4, int n4) {
    int i = blockIdx.x * blockDim.x + threadIdx.x;
    if (i >= n4) return;
    float4 kv = k4[i];          // two k-points: (kx0,ky0,kx1,ky1)
    float4 o;
    graphene_point(kv.x, kv.y, o.x, o.y);
    graphene_point(kv.z, kv.w, o.z, o.w);
    out4[i] = o;
}

extern "C" void kernel_launch(void* const* d_in, const int* in_sizes, int n_in,
                              void* d_out, int out_size, void* d_ws, size_t ws_size,
                              hipStream_t stream) {
    const float4* k4 = (const float4*)d_in[0];
    float4* out4 = (float4*)d_out;
    int n_floats = in_sizes[0];          // 2 * N_K
    int n4 = n_floats / 4;               // two k-points per thread
    int block = 256;
    int grid = (n4 + block - 1) / block;
    graphene_kernel<<<grid, block, 0, stream>>>(k4, out4, n4);
}

// Round 3
// 15.005 us; speedup vs baseline: 1.0834x; 1.0834x over previous
//
#include <hip/hip_runtime.h>
#include <math.h>

// Graphene tight-binding band energies, closed form.
// Per k-point: p = a_lat*kx/2, b = a_lat*ky/(2*sqrt(3)).
// All 9 lattice phases reduce to functions of cos(p), cos(b), sin(b):
//   f_re = -t * (2 cp cb + 2 cb^2 - 1)
//   f_im = -t * (2 sb (cp - cb))
//   e    = -2 t' * (2 cp^2 - 1 + 2 cp (4 cb^3 - 3 cb))
//   out  = (e -/+ sqrt(m^2 + f_re^2 + f_im^2)) * EV_TO_J   [ascending]
//
// Memory-bound (67 MB traffic). Grid capped at 2048 blocks, grid-stride with
// 4-way ILP (4 independent 16B loads in flight per thread), nontemporal
// stores so the write stream doesn't evict the input from L2/L3.
// Native clang vector type (not HIP float4) — nontemporal builtin requires it.

typedef float f32x4 __attribute__((ext_vector_type(4)));

namespace {
constexpr double A_LAT_D = 2.46e-10;
constexpr float C_P  = (float)(A_LAT_D * 0.5);                           // a/2
constexpr float C_B  = (float)(A_LAT_D / (2.0 * 1.7320508075688772935)); // a/(2*sqrt3)
constexpr float T_EV  = 2.8f;
constexpr float TP_EV = 0.1f;
constexpr float M_EV  = 0.05f;
constexpr float EVJ   = 1.602176634e-19f;
}

__device__ __forceinline__ void graphene_point(float kx, float ky,
                                               float& lo, float& hi) {
    float p = kx * C_P;
    float b = ky * C_B;
    float cp = __cosf(p);
    float cb = __cosf(b);
    float sb = __sinf(b);
    float cb2 = cb * cb;
    float c3b = cb * (4.0f * cb2 - 3.0f);          // cos(3b)
    float fre = -T_EV * (2.0f * cp * cb + 2.0f * cb2 - 1.0f);
    float fim = -T_EV * (2.0f * sb * (cp - cb));
    float e   = -2.0f * TP_EV * (2.0f * cp * cp - 1.0f + 2.0f * cp * c3b);
    float r   = sqrtf(M_EV * M_EV + fre * fre + fim * fim);
    lo = (e - r) * EVJ;
    hi = (e + r) * EVJ;
}

__device__ __forceinline__ f32x4 graphene_pair(f32x4 kv) {
    f32x4 o;
    float ox, oy, oz, ow;
    graphene_point(kv.x, kv.y, ox, oy);
    graphene_point(kv.z, kv.w, oz, ow);
    o.x = ox; o.y = oy; o.z = oz; o.w = ow;
    return o;
}

__global__ __launch_bounds__(256)
void graphene_kernel(const f32x4* __restrict__ k4, f32x4* __restrict__ out4, int n4) {
    int tid    = blockIdx.x * blockDim.x + threadIdx.x;
    int stride = gridDim.x * blockDim.x;

    int i = tid;
    // main loop: 4 independent loads in flight per thread
    for (; i + 3 * stride < n4; i += 4 * stride) {
        f32x4 a = k4[i];
        f32x4 b = k4[i + stride];
        f32x4 c = k4[i + 2 * stride];
        f32x4 d = k4[i + 3 * stride];
        f32x4 oa = graphene_pair(a);
        f32x4 ob = graphene_pair(b);
        f32x4 oc = graphene_pair(c);
        f32x4 od = graphene_pair(d);
        __builtin_nontemporal_store(oa, &out4[i]);
        __builtin_nontemporal_store(ob, &out4[i + stride]);
        __builtin_nontemporal_store(oc, &out4[i + 2 * stride]);
        __builtin_nontemporal_store(od, &out4[i + 3 * stride]);
    }
    // tail
    for (; i < n4; i += stride) {
        __builtin_nontemporal_store(graphene_pair(k4[i]), &out4[i]);
    }
}

extern "C" void kernel_launch(void* const* d_in, const int* in_sizes, int n_in,
                              void* d_out, int out_size, void* d_ws, size_t ws_size,
                              hipStream_t stream) {
    const f32x4* k4 = (const f32x4*)d_in[0];
    f32x4* out4 = (f32x4*)d_out;
    int n_floats = in_sizes[0];          // 2 * N_K
    int n4 = n_floats / 4;               // two k-points per f32x4
    int block = 256;
    int grid  = 2048;                    // grid-stride, ~8 blocks/CU
    graphene_kernel<<<grid, block, 0, stream>>>(k4, out4, n4);
}